// Round 9
// baseline (168.350 us; speedup 1.0000x reference)
//
#include <hip/hip_runtime.h>

#define NROWS 8192
#define DDIM 512
#define ZROWS 16384
#define BM 256
#define BN 256
#define BK 32
#define KTILES (DDIM / BK)     // 16
#define NLR_TILES 1024         // 32 x 32 (tm x lr-col-panel)
#define NTILES 1552            // + 528 upper-triangle ll tiles
#define CPX (NTILES / 8)       // 194, exact

typedef __attribute__((ext_vector_type(8))) short short8;
typedef __attribute__((ext_vector_type(4))) float f32x4;

__device__ __forceinline__ unsigned short f2bf(float f) {
  unsigned int u = __float_as_uint(f);
  u = (u + 0x7FFFu + ((u >> 16) & 1u)) >> 16;
  return (unsigned short)u;
}

// Kernel 1: per-row L2 normalize both inputs, write bf16 Z = [zl; zr],
// and compute the fp32 diagonal cosine sim dlr[i] = zl_i . zr_i.
__global__ __launch_bounds__(256) void nrm_kernel(const float* __restrict__ left,
                                                  const float* __restrict__ right,
                                                  unsigned short* __restrict__ Z,
                                                  float* __restrict__ dlr) {
  const int i = blockIdx.x;
  const int t = threadIdx.x;
  const float2 lv = ((const float2*)(left + (size_t)i * DDIM))[t];
  const float2 rv = ((const float2*)(right + (size_t)i * DDIM))[t];
  float ssl = lv.x * lv.x + lv.y * lv.y;
  float ssr = rv.x * rv.x + rv.y * rv.y;
  float slr = lv.x * rv.x + lv.y * rv.y;
#pragma unroll
  for (int m = 1; m < 64; m <<= 1) {
    ssl += __shfl_xor(ssl, m);
    ssr += __shfl_xor(ssr, m);
    slr += __shfl_xor(slr, m);
  }
  __shared__ float red[3][4];
  const int w = t >> 6;
  if ((t & 63) == 0) { red[0][w] = ssl; red[1][w] = ssr; red[2][w] = slr; }
  __syncthreads();
  ssl = red[0][0] + red[0][1] + red[0][2] + red[0][3];
  ssr = red[1][0] + red[1][1] + red[1][2] + red[1][3];
  slr = red[2][0] + red[2][1] + red[2][2] + red[2][3];
  const float invl = 1.0f / fmaxf(sqrtf(ssl), 1e-12f);
  const float invr = 1.0f / fmaxf(sqrtf(ssr), 1e-12f);
  if (t == 0) dlr[i] = slr * invl * invr;
  ushort2 zl2; zl2.x = f2bf(lv.x * invl); zl2.y = f2bf(lv.y * invl);
  ushort2 zr2; zr2.x = f2bf(rv.x * invr); zr2.y = f2bf(rv.y * invr);
  ((ushort2*)(Z + (size_t)i * DDIM))[t] = zl2;
  ((ushort2*)(Z + (size_t)(NROWS + i) * DDIM))[t] = zr2;
}

// Kernel 2: fused GEMM + exp-rowsum, ll-symmetry, 256x256 tile, BK=32,
// 8 waves (2Mx4N, wave tile 128x64), LDS 66 KB -> 2 BLOCKS/CU (16 waves/CU):
// cross-block wave overlap fills barrier/stall bubbles (the m97-ladder's
// implicit-overlap mechanism; 1-block/CU 256x256 variants all pinned at 28%).
// One barrier-pair per K-step: {stage kt+1 (4 gloads); vmcnt(4); bar;
// 12 ds_read_b128; 32 MFMA (no ks -> no dependent-consecutive MFMAs); bar}.
// 64-B LDS rows, pair-preserving slot^(row&3) swizzle on BOTH sides.
__global__ __launch_bounds__(512) void sim_kernel(const unsigned short* __restrict__ Z,
                                                  float* __restrict__ partial) {
  __shared__ __align__(16) unsigned short sA[2][BM * BK];   // 2 x 16 KB
  __shared__ __align__(16) unsigned short sB[2][BN * BK];   // 2 x 16 KB
  __shared__ float rsum[BM];
  __shared__ float csum[BM];

  // ---- tile decode with XCD-aware bijective swizzle (1552 = 8*194)
  int tm, tn; bool sym = false;
  {
    const int bid = blockIdx.x;
    const int tile = (bid & 7) * CPX + (bid >> 3);
    if (tile < NLR_TILES) {
      tm = tile >> 5; tn = 32 + (tile & 31);
    } else {
      const int b2 = tile - NLR_TILES;            // 0..527
      int i = (int)(32.5f - sqrtf(32.5f * 32.5f - 2.0f * (float)b2));
      if (i < 0) i = 0; if (i > 31) i = 31;
      while (i > 0 && (32 * i - i * (i - 1) / 2) > b2) --i;
      while (i < 31 && (32 * (i + 1) - (i + 1) * i / 2) <= b2) ++i;
      tm = i; tn = i + (b2 - (32 * i - i * (i - 1) / 2));
      sym = (tn != tm);
    }
  }

  const int t = threadIdx.x;
  const int l = t & 63;
  const int w = t >> 6;        // wave 0..7
  const int wm = w >> 2;       // 0..1  (128-row slab)
  const int wn = w & 3;        // 0..3  (64-col slab)
  const int lr = l & 15;
  const int lk = l >> 4;       // 0..3

  f32x4 acc[8][4];
#pragma unroll
  for (int a = 0; a < 8; ++a)
#pragma unroll
    for (int b = 0; b < 4; ++b)
#pragma unroll
      for (int r = 0; r < 4; ++r) acc[a][b][r] = 0.0f;

  const unsigned short* Abase = Z + (size_t)tm * BM * DDIM;
  const unsigned short* Bbase = Z + (size_t)tn * BN * DDIM;

  // Staging: 512 threads cover 128 rows x 32 k per gload (8 KB). LDS row =
  // 64 B = 4 slots of 16 B; thread t -> row h*128 + (t>>2), slot t&3,
  // LDS dest linear (base + t*16). Global source slot = (t&3)^(row&3)
  // (pair-irrelevant here: slot-level XOR, 16-B contiguous source).
  const int srow = t >> 2;                         // 0..127
  const int sslot = t & 3;

#define GLD(arr, bufi, gbase, k0, h)                                              \
  __builtin_amdgcn_global_load_lds(                                               \
      (const __attribute__((address_space(1))) void*)((gbase) +                   \
          (size_t)((h) * 128 + srow) * DDIM + (k0) +                              \
          ((sslot ^ (((h) * 128 + srow) & 3)) * 8)),                              \
      (__attribute__((address_space(3))) void*)(&arr[bufi][((h) * 128 * BK) + t * 8]), \
      16, 0, 0);

#define STAGE(bufi, k0) { GLD(sA, bufi, Abase, k0, 0) GLD(sA, bufi, Abase, k0, 1) \
                          GLD(sB, bufi, Bbase, k0, 0) GLD(sB, bufi, Bbase, k0, 1) }

#define BAR   __builtin_amdgcn_s_barrier()
#define VM4   asm volatile("s_waitcnt vmcnt(4)" ::: "memory")
#define VM0   asm volatile("s_waitcnt vmcnt(0)" ::: "memory")

  // prologue: kt0 -> buf0 (4 loads in flight)
  STAGE(0, 0);

  short8 af[8], bfr[4];

#pragma unroll
  for (int kt = 0; kt < KTILES; ++kt) {
    const int cur = kt & 1;
    // stage kt+1 into the other buffer (its readers finished at kt-1's
    // trailing barrier); counted wait: kt's 4 loads landed, kt+1's in flight.
    if (kt + 1 < KTILES) { STAGE(cur ^ 1, (kt + 1) * BK); VM4; } else { VM0; }
    BAR;
    // reads: A 8 frags, B 4 frags; swizzled slot = lk ^ (row&3)
#pragma unroll
    for (int fm = 0; fm < 8; ++fm) {
      const int row = wm * 128 + fm * 16 + lr;
      af[fm] = *(const short8*)&sA[cur][row * BK + ((lk ^ (row & 3))) * 8];
    }
#pragma unroll
    for (int fn = 0; fn < 4; ++fn) {
      const int row = wn * 64 + fn * 16 + lr;
      bfr[fn] = *(const short8*)&sB[cur][row * BK + ((lk ^ (row & 3))) * 8];
    }
    __builtin_amdgcn_s_setprio(1);
#pragma unroll
    for (int fm = 0; fm < 8; ++fm)
#pragma unroll
      for (int fn = 0; fn < 4; ++fn)
        acc[fm][fn] = __builtin_amdgcn_mfma_f32_16x16x32_bf16(af[fm], bfr[fn], acc[fm][fn], 0, 0, 0);
    __builtin_amdgcn_s_setprio(0);
    BAR;
  }

  // ---- Epilogue: e = exp(2*s); rowsums always, colsums when sym.
  // C/D layout (16x16x32): col = wn*64 + fn*16 + (lane&15),
  //                        row = wm*128 + fm*16 + (lane>>4)*4 + reg.
  if (t < BM) { rsum[t] = 0.0f; csum[t] = 0.0f; }
  __syncthreads();
  float cfn[4] = {0.0f, 0.0f, 0.0f, 0.0f};
#pragma unroll
  for (int fm = 0; fm < 8; ++fm) {
#pragma unroll
    for (int r = 0; r < 4; ++r) {
      float e0 = __expf(2.0f * acc[fm][0][r]);
      float e1 = __expf(2.0f * acc[fm][1][r]);
      float e2 = __expf(2.0f * acc[fm][2][r]);
      float e3 = __expf(2.0f * acc[fm][3][r]);
      float v = e0 + e1 + e2 + e3;
      v += __shfl_xor(v, 1);
      v += __shfl_xor(v, 2);
      v += __shfl_xor(v, 4);
      v += __shfl_xor(v, 8);
      if (lr == 0) atomicAdd(&rsum[wm * 128 + fm * 16 + lk * 4 + r], v);
      cfn[0] += e0; cfn[1] += e1; cfn[2] += e2; cfn[3] += e3;
    }
  }
  if (sym) {
#pragma unroll
    for (int fn = 0; fn < 4; ++fn) {
      cfn[fn] += __shfl_xor(cfn[fn], 16);
      cfn[fn] += __shfl_xor(cfn[fn], 32);
    }
    if (l < 16) {   // lk==0 lane per column; 2 wm-waves share a col (atomic)
      atomicAdd(&csum[wn * 64 +  0 + lr], cfn[0]);
      atomicAdd(&csum[wn * 64 + 16 + lr], cfn[1]);
      atomicAdd(&csum[wn * 64 + 32 + lr], cfn[2]);
      atomicAdd(&csum[wn * 64 + 48 + lr], cfn[3]);
    }
  }
  __syncthreads();
  if (t < BM) partial[(size_t)tn * NROWS + tm * BM + t] = rsum[t];
  if (sym && t < BM) partial[(size_t)tm * NROWS + tn * BM + t] = csum[t];
}

// Kernel 3: reduce partials, final loss.
// loss[i] = log(rowsum - e^2) - 2*dlr[i]
__global__ __launch_bounds__(256) void fin_kernel(const float* __restrict__ partial,
                                                  const float* __restrict__ dlr,
                                                  float* __restrict__ out) {
  const int i = blockIdx.x * 256 + threadIdx.x;
  float s = 0.0f;
#pragma unroll 8
  for (int p = 0; p < 64; ++p) s += partial[(size_t)p * NROWS + i];
  out[i] = logf(s - 7.38905609893065f) - 2.0f * dlr[i];
}

extern "C" void kernel_launch(void* const* d_in, const int* in_sizes, int n_in,
                              void* d_out, int out_size, void* d_ws, size_t ws_size,
                              hipStream_t stream) {
  const float* left = (const float*)d_in[0];
  const float* right = (const float*)d_in[1];
  float* out = (float*)d_out;

  unsigned short* Z = (unsigned short*)d_ws;                       // 16 MB
  char* p = (char*)d_ws + (size_t)ZROWS * DDIM * 2;
  float* dlr = (float*)p;                                          // 32 KB
  float* partial = (float*)(p + (size_t)NROWS * 4);                // 2 MB

  nrm_kernel<<<NROWS, 256, 0, stream>>>(left, right, Z, dlr);
  sim_kernel<<<NTILES, 512, 0, stream>>>(Z, partial);
  fin_kernel<<<NROWS / 256, 256, 0, stream>>>(partial, dlr, out);
}

// Round 10
// 151.632 us; speedup vs baseline: 1.1103x; 1.1103x over previous
//
#include <hip/hip_runtime.h>

#define NROWS 8192
#define DDIM 512
#define ZROWS 16384
#define BM 256
#define BN 256
#define BK 64
#define KTILES (DDIM / BK)     // 8
#define NLR_BLOCKS 1024        // 32 x 32 (tm x lr-col-panel)
#define NSYM_BLOCKS 528        // upper triangle incl diag of 32
#define NBLOCKS (NLR_BLOCKS + NSYM_BLOCKS)   // 1552

typedef __attribute__((ext_vector_type(8))) short short8;
typedef __attribute__((ext_vector_type(4))) float f32x4;

__device__ __forceinline__ unsigned short f2bf(float f) {
  unsigned int u = __float_as_uint(f);
  u = (u + 0x7FFFu + ((u >> 16) & 1u)) >> 16;
  return (unsigned short)u;
}

// Kernel 1: per-row L2 normalize both inputs, write bf16 Z = [zl; zr],
// and compute the fp32 diagonal cosine sim dlr[i] = zl_i . zr_i.
__global__ __launch_bounds__(256) void nrm_kernel(const float* __restrict__ left,
                                                  const float* __restrict__ right,
                                                  unsigned short* __restrict__ Z,
                                                  float* __restrict__ dlr) {
  const int i = blockIdx.x;
  const int t = threadIdx.x;
  const float2 lv = ((const float2*)(left + (size_t)i * DDIM))[t];
  const float2 rv = ((const float2*)(right + (size_t)i * DDIM))[t];
  float ssl = lv.x * lv.x + lv.y * lv.y;
  float ssr = rv.x * rv.x + rv.y * rv.y;
  float slr = lv.x * rv.x + lv.y * rv.y;
#pragma unroll
  for (int m = 1; m < 64; m <<= 1) {
    ssl += __shfl_xor(ssl, m);
    ssr += __shfl_xor(ssr, m);
    slr += __shfl_xor(slr, m);
  }
  __shared__ float red[3][4];
  const int w = t >> 6;
  if ((t & 63) == 0) { red[0][w] = ssl; red[1][w] = ssr; red[2][w] = slr; }
  __syncthreads();
  ssl = red[0][0] + red[0][1] + red[0][2] + red[0][3];
  ssr = red[1][0] + red[1][1] + red[1][2] + red[1][3];
  slr = red[2][0] + red[2][1] + red[2][2] + red[2][3];
  const float invl = 1.0f / fmaxf(sqrtf(ssl), 1e-12f);
  const float invr = 1.0f / fmaxf(sqrtf(ssr), 1e-12f);
  if (t == 0) dlr[i] = slr * invl * invr;
  ushort2 zl2; zl2.x = f2bf(lv.x * invl); zl2.y = f2bf(lv.y * invl);
  ushort2 zr2; zr2.x = f2bf(rv.x * invr); zr2.y = f2bf(rv.y * invr);
  ((ushort2*)(Z + (size_t)i * DDIM))[t] = zl2;
  ((ushort2*)(Z + (size_t)(NROWS + i) * DDIM))[t] = zr2;
}

// Kernel 2: fused GEMM + exp-rowsum with ll-symmetry, 8-phase schedule with
// ONE barrier per phase: [reads(p); stage(p); (vmcnt); BAR; fence; MFMA(p)].
// Mechanism: with 2 bars/phase, all waves' ds_reads occupy one global window
// and all MFMA another -> LDS port and matrix pipe alternate (serialize; 7
// structures pinned at ~28% MfmaUtil). With 1 bar/phase, a wave that finishes
// MFMA(p) immediately issues reads(p+1) on the LDS port while slower waves
// still drain MFMA(p) on the matrix pipe -> per-phase pipe overlap.
// Safety: each staged region's last reader finished >=1 barrier before the
// stage issues; VM6 sits BEFORE BAR(P4)/BAR(P8) so the following barrier
// makes the DMA-landed guarantee collective; compiler fence after each BAR
// stops C++ ds_reads hoisting above the barrier. MFMA clusters are ks-outer
// (no back-to-back dependent MFMAs, dependence distance 8).
//   stage: p1:A13(kt+1)->b1  p2:A02(kt+2)->b0 p3:B01(kt+2)->b0
//          p4:B23(kt+2)->b0+VM6  p5:A13(kt+2)->b0 p6:A02(kt+3)->b1
//          p7:B01(kt+3)->b1  p8:B23(kt+3)->b1+VM6
__global__ __launch_bounds__(512) void sim_kernel(const unsigned short* __restrict__ Z,
                                                  float* __restrict__ partial) {
  __shared__ __align__(16) unsigned short sA[2][BM * BK];   // 64 KiB
  __shared__ __align__(16) unsigned short sB[2][BN * BK];   // 64 KiB
  __shared__ float rsum[BM];
  __shared__ float csum[BM];

  // ---- block decode
  int tm, tn; bool sym = false;
  {
    const int bid = blockIdx.x;
    if (bid < NLR_BLOCKS) {
      tm = bid >> 5; tn = 32 + (bid & 31);
    } else {
      const int b2 = bid - NLR_BLOCKS;            // 0..527
      int i = (int)(32.5f - sqrtf(32.5f * 32.5f - 2.0f * (float)b2));
      if (i < 0) i = 0; if (i > 31) i = 31;
      while (i > 0 && (32 * i - i * (i - 1) / 2) > b2) --i;
      while (i < 31 && (32 * (i + 1) - (i + 1) * i / 2) <= b2) ++i;
      tm = i; tn = i + (b2 - (32 * i - i * (i - 1) / 2));
      sym = (tn != tm);
    }
  }

  const int t = threadIdx.x;
  const int l = t & 63;
  const int w = t >> 6;        // wave 0..7
  const int wm = w >> 2;       // 0..1  (128-row slab)
  const int wn = w & 3;        // 0..3  (64-col slab)
  const int lr = l & 15;
  const int lk = l >> 4;       // 0..3

  f32x4 acc[8][4];
#pragma unroll
  for (int a = 0; a < 8; ++a)
#pragma unroll
    for (int b = 0; b < 4; ++b)
#pragma unroll
      for (int r = 0; r < 4; ++r) acc[a][b][r] = 0.0f;

  const unsigned short* Abase = Z + (size_t)tm * BM * DDIM;
  const unsigned short* Bbase = Z + (size_t)tn * BN * DDIM;

  // Staging: element e = j*512 + t; LDS slot-linear; global source slot
  // pre-swizzled by row&7; matching XOR on ds_read (verified conflict-free).
  const int srow = t >> 3;                       // 0..63
  const int scol = ((t & 7) ^ (srow & 7)) * 8;   // swizzled source element col

#define STAGE_AJ(bufi, k0, j)                                                     \
  __builtin_amdgcn_global_load_lds(                                               \
      (const __attribute__((address_space(1))) void*)(Abase +                     \
          (size_t)((j) * 64 + srow) * DDIM + (k0) + scol),                        \
      (__attribute__((address_space(3))) void*)(&sA[bufi][((j) * 512 + t) * 8]),  \
      16, 0, 0);
#define STAGE_BJ(bufi, k0, j)                                                     \
  __builtin_amdgcn_global_load_lds(                                               \
      (const __attribute__((address_space(1))) void*)(Bbase +                     \
          (size_t)((j) * 64 + srow) * DDIM + (k0) + scol),                        \
      (__attribute__((address_space(3))) void*)(&sB[bufi][((j) * 512 + t) * 8]),  \
      16, 0, 0);
#define STAGE_A02(b, k0) { STAGE_AJ(b, k0, 0) STAGE_AJ(b, k0, 2) }
#define STAGE_A13(b, k0) { STAGE_AJ(b, k0, 1) STAGE_AJ(b, k0, 3) }
#define STAGE_B01(b, k0) { STAGE_BJ(b, k0, 0) STAGE_BJ(b, k0, 1) }
#define STAGE_B23(b, k0) { STAGE_BJ(b, k0, 2) STAGE_BJ(b, k0, 3) }

  short8 af[4][2], ag[4][2], bf[4][2];

#define DS_A(dst, bufi, fmb)                                                       \
  _Pragma("unroll")                                                                \
  for (int fm = 0; fm < 4; ++fm)                                                   \
    _Pragma("unroll")                                                              \
    for (int ks = 0; ks < 2; ++ks) {                                               \
      const int row = wm * 128 + ((fmb) + fm) * 16 + lr;                           \
      dst[fm][ks] = *(const short8*)&sA[bufi][row * BK + ((ks * 4 + lk) ^ (lr & 7)) * 8]; \
    }

#define DS_B2(bufi, fnb)                                                           \
  _Pragma("unroll")                                                                \
  for (int fn = 0; fn < 2; ++fn)                                                   \
    _Pragma("unroll")                                                              \
    for (int ks = 0; ks < 2; ++ks) {                                               \
      const int row = wn * 64 + ((fnb) + fn) * 16 + lr;                            \
      bf[(fnb) + fn][ks] = *(const short8*)&sB[bufi][row * BK + ((ks * 4 + lk) ^ (lr & 7)) * 8]; \
    }

// ks OUTER: consecutive MFMAs hit distinct accumulators (dep distance 8).
#define MFMA16(A, fmb, fnb)                                                        \
  __builtin_amdgcn_s_setprio(1);                                                   \
  _Pragma("unroll")                                                                \
  for (int ks = 0; ks < 2; ++ks)                                                   \
    _Pragma("unroll")                                                              \
    for (int fm = 0; fm < 4; ++fm)                                                 \
      _Pragma("unroll")                                                            \
      for (int fn = 0; fn < 2; ++fn)                                               \
        acc[(fmb) + fm][(fnb) + fn] =                                              \
            __builtin_amdgcn_mfma_f32_16x16x32_bf16(A[fm][ks], bf[(fnb) + fn][ks], \
                                                    acc[(fmb) + fm][(fnb) + fn],   \
                                                    0, 0, 0);                      \
  __builtin_amdgcn_s_setprio(0);

#define BARF  { __builtin_amdgcn_s_barrier(); asm volatile("" ::: "memory"); }
#define VM6   asm volatile("s_waitcnt vmcnt(6)" ::: "memory")
#define VM0   asm volatile("s_waitcnt vmcnt(0)" ::: "memory")

  // prologue: kt0 fully + kt1 {A02,B01,B23}; VM6 => kt0 landed per-wave;
  // BARF makes it collective.
  STAGE_A02(0, 0); STAGE_A13(0, 0); STAGE_B01(0, 0); STAGE_B23(0, 0);
  STAGE_A02(1, BK); STAGE_B01(1, BK); STAGE_B23(1, BK);
  VM6;
  BARF;

#pragma unroll
  for (int it = 0; it < 4; ++it) {
    const int kt = 2 * it;
    // ---- P1: reads af+bf01 (buf0) | stage A13(kt+1)->buf1 | BAR | MFMA
    DS_A(af, 0, 0); DS_B2(0, 0);
    STAGE_A13(1, (kt + 1) * BK);
    BARF;
    MFMA16(af, 0, 0);
    // ---- P2: reads bf23 (buf0) | stage A02(kt+2)->buf0
    DS_B2(0, 2);
    if (kt + 2 < KTILES) STAGE_A02(0, (kt + 2) * BK);
    BARF;
    MFMA16(af, 0, 2);
    // ---- P3: reads ag (buf0) | stage B01(kt+2)->buf0
    DS_A(ag, 0, 4);
    if (kt + 2 < KTILES) STAGE_B01(0, (kt + 2) * BK);
    BARF;
    MFMA16(ag, 4, 0);
    // ---- P4: stage B23(kt+2)->buf0 | counted vmcnt BEFORE the barrier
    if (kt + 2 < KTILES) { STAGE_B23(0, (kt + 2) * BK); VM6; } else { VM0; }
    BARF;
    MFMA16(ag, 4, 2);
    // ---- P5: reads af+bf01 (buf1) | stage A13(kt+2)->buf0
    DS_A(af, 1, 0); DS_B2(1, 0);
    if (kt + 2 < KTILES) STAGE_A13(0, (kt + 2) * BK);
    BARF;
    MFMA16(af, 0, 0);
    // ---- P6: reads bf23 (buf1) | stage A02(kt+3)->buf1
    DS_B2(1, 2);
    if (kt + 3 < KTILES) STAGE_A02(1, (kt + 3) * BK);
    BARF;
    MFMA16(af, 0, 2);
    // ---- P7: reads ag (buf1) | stage B01(kt+3)->buf1
    DS_A(ag, 1, 4);
    if (kt + 3 < KTILES) STAGE_B01(1, (kt + 3) * BK);
    BARF;
    MFMA16(ag, 4, 0);
    // ---- P8: stage B23(kt+3)->buf1 | counted vmcnt BEFORE the barrier
    if (kt + 3 < KTILES) { STAGE_B23(1, (kt + 3) * BK); VM6; } else { VM0; }
    BARF;
    MFMA16(ag, 4, 2);
  }

  // ---- Epilogue: e = exp(2*s); rowsums always, colsums when sym.
  // C/D layout (16x16x32): col = lane&15, row = (lane>>4)*4 + reg.
  // All DMA drained (VM0 at it=3 P4/P8); dedicated LDS reductions.
  if (t < BM) { rsum[t] = 0.0f; csum[t] = 0.0f; }
  __syncthreads();
  float c0 = 0.0f, c1 = 0.0f, c2 = 0.0f, c3 = 0.0f;
#pragma unroll
  for (int fm = 0; fm < 8; ++fm) {
#pragma unroll
    for (int r = 0; r < 4; ++r) {
      float e0 = __expf(2.0f * acc[fm][0][r]);
      float e1 = __expf(2.0f * acc[fm][1][r]);
      float e2 = __expf(2.0f * acc[fm][2][r]);
      float e3 = __expf(2.0f * acc[fm][3][r]);
      float v = e0 + e1 + e2 + e3;
      v += __shfl_xor(v, 1);
      v += __shfl_xor(v, 2);
      v += __shfl_xor(v, 4);
      v += __shfl_xor(v, 8);
      if (lr == 0) atomicAdd(&rsum[wm * 128 + fm * 16 + lk * 4 + r], v);
      c0 += e0; c1 += e1; c2 += e2; c3 += e3;
    }
  }
  if (sym) {
    c0 += __shfl_xor(c0, 16); c0 += __shfl_xor(c0, 32);
    c1 += __shfl_xor(c1, 16); c1 += __shfl_xor(c1, 32);
    c2 += __shfl_xor(c2, 16); c2 += __shfl_xor(c2, 32);
    c3 += __shfl_xor(c3, 16); c3 += __shfl_xor(c3, 32);
    if (l < 16) {   // one lane per column per wave; 2 waves (wm) share a col
      atomicAdd(&csum[wn * 64 +  0 + lr], c0);
      atomicAdd(&csum[wn * 64 + 16 + lr], c1);
      atomicAdd(&csum[wn * 64 + 32 + lr], c2);
      atomicAdd(&csum[wn * 64 + 48 + lr], c3);
    }
  }
  __syncthreads();
  if (t < BM) partial[(size_t)tn * NROWS + tm * BM + t] = rsum[t];
  if (sym && t < BM) partial[(size_t)tm * NROWS + tn * BM + t] = csum[t];
}

// Kernel 3: reduce partials, final loss.
// loss[i] = log(rowsum - e^2) - 2*dlr[i]
__global__ __launch_bounds__(256) void fin_kernel(const float* __restrict__ partial,
                                                  const float* __restrict__ dlr,
                                                  float* __restrict__ out) {
  const int i = blockIdx.x * 256 + threadIdx.x;
  float s = 0.0f;
#pragma unroll 8
  for (int p = 0; p < 64; ++p) s += partial[(size_t)p * NROWS + i];
  out[i] = logf(s - 7.38905609893065f) - 2.0f * dlr[i];
}

extern "C" void kernel_launch(void* const* d_in, const int* in_sizes, int n_in,
                              void* d_out, int out_size, void* d_ws, size_t ws_size,
                              hipStream_t stream) {
  const float* left = (const float*)d_in[0];
  const float* right = (const float*)d_in[1];
  float* out = (float*)d_out;

  unsigned short* Z = (unsigned short*)d_ws;                       // 16 MB
  char* p = (char*)d_ws + (size_t)ZROWS * DDIM * 2;
  float* dlr = (float*)p;                                          // 32 KB
  float* partial = (float*)(p + (size_t)NROWS * 4);                // 2 MB

  nrm_kernel<<<NROWS, 256, 0, stream>>>(left, right, Z, dlr);
  sim_kernel<<<NBLOCKS, 512, 0, stream>>>(Z, partial);
  fin_kernel<<<NROWS / 256, 256, 0, stream>>>(partial, dlr, out);
}